// Round 6
// baseline (385.447 us; speedup 1.0000x reference)
//
#include <hip/hip_runtime.h>
#include <hip/hip_fp16.h>

// GCN forward: 3x (GEMM -> normalized scatter-sum -> bias -> relu[except last])
// All gathered/streamed intermediates are fp16 (gather table 12.8 MB; agg<->gemm
// interfaces fp16). Edge list is 4 B/edge (src only); norm = dinv[src]*dinv[dst]
// recomputed in agg from the L2-resident 400 KB dinv table. CSR built with zero
// global atomics: coarse 256-node buckets + single merged fine pass.

#define ALIGN256(x) (((size_t)(x) + 255) & ~(size_t)255)

// ---------------- coarse histogram ----------------

__global__ __launch_bounds__(256) void k_coarse(const int* __restrict__ ei,
                                                int* __restrict__ ccnt,
                                                int E, int NBUK) {
    __shared__ int h[512];
    int t = threadIdx.x;
    for (int i = t; i < NBUK; i += 256) h[i] = 0;
    __syncthreads();
    int e0 = blockIdx.x * 8192;
    int e1 = min(e0 + 8192, E);
    for (int e = e0 + t; e < e1; e += 256) atomicAdd(&h[ei[E + e] >> 8], 1);
    __syncthreads();
    for (int i = t; i < NBUK; i += 256) {
        int c = h[i];
        if (c) atomicAdd(&ccnt[i], c);
    }
}

// ---------------- scan of coarse counts (single block, <=512 buckets) -------

__global__ __launch_bounds__(256) void k_cscan(const int* __restrict__ ccnt,
                                               int* __restrict__ cbase,
                                               int* __restrict__ cpos,
                                               int* __restrict__ row_start,
                                               int NBUK, int E, int N) {
    __shared__ int sd[256];
    int t = threadIdx.x;
    int i0 = 2 * t, i1 = 2 * t + 1;
    int v0 = (i0 < NBUK) ? ccnt[i0] : 0;
    int v1 = (i1 < NBUK) ? ccnt[i1] : 0;
    int s = v0 + v1;
    sd[t] = s;
    __syncthreads();
    for (int off = 1; off < 256; off <<= 1) {
        int u = (t >= off) ? sd[t - off] : 0;
        __syncthreads();
        sd[t] += u;
        __syncthreads();
    }
    int base = sd[t] - s;
    if (i0 < NBUK) { cbase[i0] = base;      cpos[i0] = base; }
    if (i1 < NBUK) { cbase[i1] = base + v0; cpos[i1] = base + v0; }
    if (t == 0) { cbase[NBUK] = E; row_start[N] = E; }
}

// ---------------- pass A: coarse scatter; stage entry = (dst&255)<<24 | src -

__global__ __launch_bounds__(256) void k_passA(const int* __restrict__ ei,
                                               int* __restrict__ cpos,
                                               unsigned int* __restrict__ stage,
                                               int E, int NBUK) {
    __shared__ int h[512];
    __shared__ int base[512];
    int t = threadIdx.x;
    for (int i = t; i < NBUK; i += 256) h[i] = 0;
    __syncthreads();
    int e0 = blockIdx.x * 8192;
    int e1 = min(e0 + 8192, E);
    for (int e = e0 + t; e < e1; e += 256) atomicAdd(&h[ei[E + e] >> 8], 1);
    __syncthreads();
    for (int b = t; b < NBUK; b += 256) {
        int c = h[b];
        base[b] = c ? atomicAdd(&cpos[b], c) : 0;
        h[b] = 0;
    }
    __syncthreads();
    for (int e = e0 + t; e < e1; e += 256) {
        unsigned int s = (unsigned int)ei[e];
        int d = ei[E + e];
        int b = d >> 8;
        int off = base[b] + atomicAdd(&h[b], 1);
        stage[off] = ((unsigned int)(d & 255) << 24) | s;
    }
}

// ---------------- fine: per-bucket count+scan -> row_start/dinv, then scatter
// One block per 256-node bucket; everything bucket-local (LDS); ep = src only.

__global__ __launch_bounds__(256) void k_fine(const unsigned int* __restrict__ stage,
                                              const int* __restrict__ cbase,
                                              int* __restrict__ row_start,
                                              float* __restrict__ dinv,
                                              int* __restrict__ ep, int N) {
    __shared__ int cnt[256];
    __shared__ int sd[256];
    __shared__ int lpos[256];
    int b = blockIdx.x;
    int n0 = b << 8;
    int t = threadIdx.x;
    cnt[t] = 0;
    __syncthreads();
    int s0 = cbase[b], s1 = cbase[b + 1];
    for (int j = s0 + t; j < s1; j += 256)
        atomicAdd(&cnt[__builtin_nontemporal_load(&stage[j]) >> 24], 1);
    __syncthreads();
    int c = cnt[t];
    sd[t] = c;
    __syncthreads();
    for (int off = 1; off < 256; off <<= 1) {
        int u = (t >= off) ? sd[t - off] : 0;
        __syncthreads();
        sd[t] += u;
        __syncthreads();
    }
    int rs = s0 + sd[t] - c;
    int node = n0 + t;
    if (node < N) {
        row_start[node] = rs;
        dinv[node] = 1.0f / sqrtf((float)(c + 1));   // +1 self-loop
    }
    lpos[t] = rs;
    __syncthreads();
    for (int j = s0 + t; j < s1; j += 256) {
        unsigned int v = stage[j];        // L2-hot from first loop
        int li = v >> 24;
        int slot = atomicAdd(&lpos[li], 1);
        ep[slot] = (int)(v & 0xFFFFFF);
    }
}

// ---------------- GEMM (fp32 input): Y[N,OUT](fp16) = X[N,K] @ W[K,OUT] -----
// 64x64 tile per 256-thread block, 4x4 register tile, K tiled by 32.
// Thread rows {ty,ty+16,ty+32,ty+48}: A-tile LDS reads spread all 32 banks.

template <int K, int OUT>
__global__ __launch_bounds__(256) void k_gemm32(const float* __restrict__ X,
                                                const float* __restrict__ W,
                                                __half* __restrict__ Y, int N) {
    __shared__ float Wl[32 * 64];    // 8 KB slab, zero-padded cols
    __shared__ float Al[64 * 36];    // 9 KB, padded stride 36
    int tid = threadIdx.x;
    int tx = tid & 15;
    int ty = tid >> 4;
    int row0 = blockIdx.x * 64;

    float acc[4][4];
#pragma unroll
    for (int i = 0; i < 4; i++)
#pragma unroll
        for (int j = 0; j < 4; j++) acc[i][j] = 0.0f;

    for (int kt = 0; kt < K; kt += 32) {
        __syncthreads();
#pragma unroll
        for (int it = 0; it < 2; it++) {
            int idx = tid + it * 256;
            int k = idx >> 4;
            int c4 = (idx & 15) << 2;
            float4 v = make_float4(0.f, 0.f, 0.f, 0.f);
            if (c4 < OUT) v = *(const float4*)&W[(size_t)(kt + k) * OUT + c4];
            *(float4*)&Wl[k * 64 + c4] = v;
        }
#pragma unroll
        for (int it = 0; it < 2; it++) {
            int vid = tid + it * 256;
            int r = vid >> 3;
            int kk = (vid & 7) << 2;
            int row = row0 + r;
            float4 v = make_float4(0.f, 0.f, 0.f, 0.f);
            if (row < N) v = *(const float4*)&X[(size_t)row * K + kt + kk];
            *(float4*)&Al[r * 36 + kk] = v;
        }
        __syncthreads();
#pragma unroll
        for (int k = 0; k < 32; k += 4) {
            float4 a[4], w[4];
#pragma unroll
            for (int i = 0; i < 4; i++) a[i] = *(const float4*)&Al[(ty + 16 * i) * 36 + k];
#pragma unroll
            for (int j = 0; j < 4; j++) w[j] = *(const float4*)&Wl[(k + j) * 64 + 4 * tx];
#pragma unroll
            for (int i = 0; i < 4; i++) {
                acc[i][0] += a[i].x * w[0].x; acc[i][1] += a[i].x * w[0].y;
                acc[i][2] += a[i].x * w[0].z; acc[i][3] += a[i].x * w[0].w;
                acc[i][0] += a[i].y * w[1].x; acc[i][1] += a[i].y * w[1].y;
                acc[i][2] += a[i].y * w[1].z; acc[i][3] += a[i].y * w[1].w;
                acc[i][0] += a[i].z * w[2].x; acc[i][1] += a[i].z * w[2].y;
                acc[i][2] += a[i].z * w[2].z; acc[i][3] += a[i].z * w[2].w;
                acc[i][0] += a[i].w * w[3].x; acc[i][1] += a[i].w * w[3].y;
                acc[i][2] += a[i].w * w[3].z; acc[i][3] += a[i].w * w[3].w;
            }
        }
    }

    int c0 = 4 * tx;
#pragma unroll
    for (int i = 0; i < 4; i++) {
        int row = row0 + ty + 16 * i;
        if (row < N && c0 + 4 <= OUT) {
            __half2 p0 = __floats2half2_rn(acc[i][0], acc[i][1]);
            __half2 p1 = __floats2half2_rn(acc[i][2], acc[i][3]);
            uint2 pk = make_uint2(*(unsigned int*)&p0, *(unsigned int*)&p1);
            *(uint2*)&Y[(size_t)row * OUT + c0] = pk;
        }
    }
}

// ---------------- GEMM (fp16 input, K=64): Y[N,OUT](fp16) = X @ W -----------
// Full 64-K staged once; A converted fp16->fp32 during staging so the FMA
// loop is identical. LDS: 16 KB W + 17 KB A.

template <int OUT>
__global__ __launch_bounds__(256) void k_gemm16(const __half* __restrict__ X,
                                                const float* __restrict__ W,
                                                __half* __restrict__ Y, int N) {
    __shared__ float Wl[64 * 64];    // 16 KB, zero-padded cols
    __shared__ float Al[64 * 68];    // 17 KB, padded stride 68 (68%32==4)
    int tid = threadIdx.x;
    int tx = tid & 15;
    int ty = tid >> 4;
    int row0 = blockIdx.x * 64;

#pragma unroll
    for (int it = 0; it < 4; it++) {
        int idx = tid + it * 256;
        int k = idx >> 4;
        int c4 = (idx & 15) << 2;
        float4 v = make_float4(0.f, 0.f, 0.f, 0.f);
        if (c4 < OUT) v = *(const float4*)&W[(size_t)k * OUT + c4];
        *(float4*)&Wl[k * 64 + c4] = v;
    }
#pragma unroll
    for (int it = 0; it < 2; it++) {
        int idx = tid + it * 256;
        int r = idx >> 3;
        int c8 = (idx & 7) << 3;
        int row = row0 + r;
        uint4 hv = make_uint4(0, 0, 0, 0);
        if (row < N) hv = *(const uint4*)&X[(size_t)row * 64 + c8];
        __half2* hp = (__half2*)&hv;
        float2 f0 = __half22float2(hp[0]);
        float2 f1 = __half22float2(hp[1]);
        float2 f2 = __half22float2(hp[2]);
        float2 f3 = __half22float2(hp[3]);
        *(float4*)&Al[r * 68 + c8]     = make_float4(f0.x, f0.y, f1.x, f1.y);
        *(float4*)&Al[r * 68 + c8 + 4] = make_float4(f2.x, f2.y, f3.x, f3.y);
    }
    __syncthreads();

    float acc[4][4];
#pragma unroll
    for (int i = 0; i < 4; i++)
#pragma unroll
        for (int j = 0; j < 4; j++) acc[i][j] = 0.0f;

#pragma unroll
    for (int k = 0; k < 64; k += 4) {
        float4 a[4], w[4];
#pragma unroll
        for (int i = 0; i < 4; i++) a[i] = *(const float4*)&Al[(ty + 16 * i) * 68 + k];
#pragma unroll
        for (int j = 0; j < 4; j++) w[j] = *(const float4*)&Wl[(k + j) * 64 + 4 * tx];
#pragma unroll
        for (int i = 0; i < 4; i++) {
            acc[i][0] += a[i].x * w[0].x; acc[i][1] += a[i].x * w[0].y;
            acc[i][2] += a[i].x * w[0].z; acc[i][3] += a[i].x * w[0].w;
            acc[i][0] += a[i].y * w[1].x; acc[i][1] += a[i].y * w[1].y;
            acc[i][2] += a[i].y * w[1].z; acc[i][3] += a[i].y * w[1].w;
            acc[i][0] += a[i].z * w[2].x; acc[i][1] += a[i].z * w[2].y;
            acc[i][2] += a[i].z * w[2].z; acc[i][3] += a[i].z * w[2].w;
            acc[i][0] += a[i].w * w[3].x; acc[i][1] += a[i].w * w[3].y;
            acc[i][2] += a[i].w * w[3].z; acc[i][3] += a[i].w * w[3].w;
        }
    }

    int c0 = 4 * tx;
#pragma unroll
    for (int i = 0; i < 4; i++) {
        int row = row0 + ty + 16 * i;
        if (row < N && c0 + 4 <= OUT) {
            __half2 p0 = __floats2half2_rn(acc[i][0], acc[i][1]);
            __half2 p1 = __floats2half2_rn(acc[i][2], acc[i][3]);
            uint2 pk = make_uint2(*(unsigned int*)&p0, *(unsigned int*)&p1);
            *(uint2*)&Y[(size_t)row * OUT + c0] = pk;
        }
    }
}

// ---------------- Aggregation (fp16 gather, fp32 accumulate) ----------------
// 8 lanes/node (lane = 8 fp16 feats = 16B), 8 nodes/wave, unroll x8.
// norm recomputed from L2-resident dinv; ep streamed non-temporally.

__device__ __forceinline__ void fma8(float4& a0, float4& a1, uint4 hv, float w) {
    __half2* hp = (__half2*)&hv;
    float2 f0 = __half22float2(hp[0]);
    float2 f1 = __half22float2(hp[1]);
    float2 f2 = __half22float2(hp[2]);
    float2 f3 = __half22float2(hp[3]);
    a0.x += f0.x * w; a0.y += f0.y * w; a0.z += f1.x * w; a0.w += f1.y * w;
    a1.x += f2.x * w; a1.y += f2.y * w; a1.z += f3.x * w; a1.w += f3.y * w;
}

template <int NV, int F, int RELU, typename OutT>
__global__ __launch_bounds__(256) void k_agg(const __half* __restrict__ H,
                                             const int* __restrict__ row_start,
                                             const int* __restrict__ ep,
                                             const float* __restrict__ dinv,
                                             const float* __restrict__ bias,
                                             OutT* __restrict__ out, int N) {
    int tid = threadIdx.x;
    int lane = tid & 63;
    int sub = lane >> 3;        // node within wave (0..7)
    int lq = lane & 7;          // 8-feature chunk
    int node = blockIdx.x * 32 + (tid >> 6) * 8 + sub;
    if (node >= N) return;
    const bool act = (NV == 8) || (lq < NV);

    int jb = row_start[node];
    int je = row_start[node + 1];
    float dv = dinv[node];

    float4 a0 = make_float4(0.f, 0.f, 0.f, 0.f);
    float4 a1 = make_float4(0.f, 0.f, 0.f, 0.f);
    if (act) {
        uint4 hv = *(const uint4*)&H[(size_t)node * F + 8 * lq];
        fma8(a0, a1, hv, dv * dv);
    }

    int j = jb;
    for (; j + 8 <= je; j += 8) {
        int s0 = __builtin_nontemporal_load(&ep[j]);
        int s1 = __builtin_nontemporal_load(&ep[j + 1]);
        int s2 = __builtin_nontemporal_load(&ep[j + 2]);
        int s3 = __builtin_nontemporal_load(&ep[j + 3]);
        int s4 = __builtin_nontemporal_load(&ep[j + 4]);
        int s5 = __builtin_nontemporal_load(&ep[j + 5]);
        int s6 = __builtin_nontemporal_load(&ep[j + 6]);
        int s7 = __builtin_nontemporal_load(&ep[j + 7]);
        if (act) {
            uint4 h0 = *(const uint4*)&H[(size_t)s0 * F + 8 * lq];
            uint4 h1 = *(const uint4*)&H[(size_t)s1 * F + 8 * lq];
            uint4 h2 = *(const uint4*)&H[(size_t)s2 * F + 8 * lq];
            uint4 h3 = *(const uint4*)&H[(size_t)s3 * F + 8 * lq];
            uint4 h4 = *(const uint4*)&H[(size_t)s4 * F + 8 * lq];
            uint4 h5 = *(const uint4*)&H[(size_t)s5 * F + 8 * lq];
            uint4 h6 = *(const uint4*)&H[(size_t)s6 * F + 8 * lq];
            uint4 h7 = *(const uint4*)&H[(size_t)s7 * F + 8 * lq];
            float w0 = dinv[s0] * dv, w1 = dinv[s1] * dv;
            float w2 = dinv[s2] * dv, w3 = dinv[s3] * dv;
            float w4 = dinv[s4] * dv, w5 = dinv[s5] * dv;
            float w6 = dinv[s6] * dv, w7 = dinv[s7] * dv;
            fma8(a0, a1, h0, w0); fma8(a0, a1, h1, w1);
            fma8(a0, a1, h2, w2); fma8(a0, a1, h3, w3);
            fma8(a0, a1, h4, w4); fma8(a0, a1, h5, w5);
            fma8(a0, a1, h6, w6); fma8(a0, a1, h7, w7);
        }
    }
    for (; j + 2 <= je; j += 2) {
        int s0 = __builtin_nontemporal_load(&ep[j]);
        int s1 = __builtin_nontemporal_load(&ep[j + 1]);
        if (act) {
            uint4 h0 = *(const uint4*)&H[(size_t)s0 * F + 8 * lq];
            uint4 h1 = *(const uint4*)&H[(size_t)s1 * F + 8 * lq];
            fma8(a0, a1, h0, dinv[s0] * dv);
            fma8(a0, a1, h1, dinv[s1] * dv);
        }
    }
    if (j < je) {
        int s0 = __builtin_nontemporal_load(&ep[j]);
        if (act) {
            uint4 h = *(const uint4*)&H[(size_t)s0 * F + 8 * lq];
            fma8(a0, a1, h, dinv[s0] * dv);
        }
    }

    if (act) {
        float4 b0 = *(const float4*)&bias[8 * lq];
        float4 b1 = *(const float4*)&bias[8 * lq + 4];
        a0.x += b0.x; a0.y += b0.y; a0.z += b0.z; a0.w += b0.w;
        a1.x += b1.x; a1.y += b1.y; a1.z += b1.z; a1.w += b1.w;
        if (RELU) {
            a0.x = fmaxf(a0.x, 0.f); a0.y = fmaxf(a0.y, 0.f);
            a0.z = fmaxf(a0.z, 0.f); a0.w = fmaxf(a0.w, 0.f);
            a1.x = fmaxf(a1.x, 0.f); a1.y = fmaxf(a1.y, 0.f);
            a1.z = fmaxf(a1.z, 0.f); a1.w = fmaxf(a1.w, 0.f);
        }
        if constexpr (sizeof(OutT) == 2) {
            __half2 p0 = __floats2half2_rn(a0.x, a0.y);
            __half2 p1 = __floats2half2_rn(a0.z, a0.w);
            __half2 p2 = __floats2half2_rn(a1.x, a1.y);
            __half2 p3 = __floats2half2_rn(a1.z, a1.w);
            uint4 pk = make_uint4(*(unsigned int*)&p0, *(unsigned int*)&p1,
                                  *(unsigned int*)&p2, *(unsigned int*)&p3);
            *(uint4*)&out[(size_t)node * F + 8 * lq] = pk;
        } else {
            *(float4*)&out[(size_t)node * F + 8 * lq] = a0;
            *(float4*)&out[(size_t)node * F + 8 * lq + 4] = a1;
        }
    }
}

// ---------------- launch ----------------

extern "C" void kernel_launch(void* const* d_in, const int* in_sizes, int n_in,
                              void* d_out, int out_size, void* d_ws, size_t ws_size,
                              hipStream_t stream) {
    const float* x  = (const float*)d_in[0];
    const int*   ei = (const int*)d_in[1];
    const float* W0 = (const float*)d_in[2];
    const float* b0 = (const float*)d_in[3];
    const float* W1 = (const float*)d_in[4];
    const float* b1 = (const float*)d_in[5];
    const float* W2 = (const float*)d_in[6];
    const float* b2 = (const float*)d_in[7];
    float* out = (float*)d_out;

    const int N = in_sizes[0] / 128;
    const int E = in_sizes[1] / 2;
    const int NBUK = (N + 255) >> 8;   // coarse buckets of 256 nodes (<=512)

    char* w = (char*)d_ws;
    size_t off = 0;
    int*    ccnt      = (int*)(w + off);    off = ALIGN256(off + (size_t)NBUK * 4);
    int*    cbase     = (int*)(w + off);    off = ALIGN256(off + (size_t)(NBUK + 1) * 4);
    int*    cpos      = (int*)(w + off);    off = ALIGN256(off + (size_t)NBUK * 4);
    int*    row_start = (int*)(w + off);    off = ALIGN256(off + (size_t)(N + 1) * 4);
    float*  dinv      = (float*)(w + off);  off = ALIGN256(off + (size_t)N * 4);
    int*    ep        = (int*)(w + off);    off = ALIGN256(off + (size_t)E * 4);
    __half* bufH      = (__half*)(w + off); off = ALIGN256(off + (size_t)N * 64 * 2);
    __half* bufG      = (__half*)(w + off); off = ALIGN256(off + (size_t)N * 64 * 2);
    unsigned int* stage = (unsigned int*)bufG;   // dead before agg1 writes bufG

    const int gGemm = (N + 63) / 64;
    const int gAgg  = (N + 31) / 32;
    const int gPA   = (E + 8191) / 8192;

    hipMemsetAsync(ccnt, 0, (size_t)NBUK * 4, stream);
    k_gemm32<128, 64><<<gGemm, 256, 0, stream>>>(x, W0, bufH, N);
    k_coarse<<<gPA, 256, 0, stream>>>(ei, ccnt, E, NBUK);
    k_cscan<<<1, 256, 0, stream>>>(ccnt, cbase, cpos, row_start, NBUK, E, N);
    k_passA<<<gPA, 256, 0, stream>>>(ei, cpos, stage, E, NBUK);
    k_fine<<<NBUK, 256, 0, stream>>>(stage, cbase, row_start, dinv, ep, N);

    k_agg<8, 64, 1, __half><<<gAgg, 256, 0, stream>>>(bufH, row_start, ep, dinv, b0, bufG, N);
    k_gemm16<64><<<gGemm, 256, 0, stream>>>(bufG, W1, bufH, N);
    k_agg<8, 64, 1, __half><<<gAgg, 256, 0, stream>>>(bufH, row_start, ep, dinv, b1, bufG, N);
    k_gemm16<40><<<gGemm, 256, 0, stream>>>(bufG, W2, bufH, N);
    k_agg<5, 40, 0, float><<<gAgg, 256, 0, stream>>>(bufH, row_start, ep, dinv, b2, out, N);
}

// Round 7
// 373.007 us; speedup vs baseline: 1.0333x; 1.0333x over previous
//
#include <hip/hip_runtime.h>
#include <hip/hip_fp16.h>

// GCN forward: 3x (GEMM -> normalized scatter-sum -> bias -> relu[except last])
// Gather table and agg<->gemm interfaces are fp16. ep = (src, norm) int2 —
// precomputed norm; R6 showed per-edge dinv[src] gathers regress (latency-bound,
// -17% occupancy) vs streaming 8B/edge sequentially. CSR built with zero global
// atomics: coarse 256-node buckets + B1 (counts->row_start/dinv) + B2 (scatter).

#define ALIGN256(x) (((size_t)(x) + 255) & ~(size_t)255)

// ---------------- coarse histogram ----------------

__global__ __launch_bounds__(256) void k_coarse(const int* __restrict__ ei,
                                                int* __restrict__ ccnt,
                                                int E, int NBUK) {
    __shared__ int h[512];
    int t = threadIdx.x;
    for (int i = t; i < NBUK; i += 256) h[i] = 0;
    __syncthreads();
    int e0 = blockIdx.x * 8192;
    int e1 = min(e0 + 8192, E);
    for (int e = e0 + t; e < e1; e += 256) atomicAdd(&h[ei[E + e] >> 8], 1);
    __syncthreads();
    for (int i = t; i < NBUK; i += 256) {
        int c = h[i];
        if (c) atomicAdd(&ccnt[i], c);
    }
}

// ---------------- scan of coarse counts (single block, <=512 buckets) -------

__global__ __launch_bounds__(256) void k_cscan(const int* __restrict__ ccnt,
                                               int* __restrict__ cbase,
                                               int* __restrict__ cpos,
                                               int* __restrict__ row_start,
                                               int NBUK, int E, int N) {
    __shared__ int sd[256];
    int t = threadIdx.x;
    int i0 = 2 * t, i1 = 2 * t + 1;
    int v0 = (i0 < NBUK) ? ccnt[i0] : 0;
    int v1 = (i1 < NBUK) ? ccnt[i1] : 0;
    int s = v0 + v1;
    sd[t] = s;
    __syncthreads();
    for (int off = 1; off < 256; off <<= 1) {
        int u = (t >= off) ? sd[t - off] : 0;
        __syncthreads();
        sd[t] += u;
        __syncthreads();
    }
    int base = sd[t] - s;
    if (i0 < NBUK) { cbase[i0] = base;      cpos[i0] = base; }
    if (i1 < NBUK) { cbase[i1] = base + v0; cpos[i1] = base + v0; }
    if (t == 0) { cbase[NBUK] = E; row_start[N] = E; }
}

// ---------------- pass A: coarse scatter; stage entry = (dst&255)<<24 | src -

__global__ __launch_bounds__(256) void k_passA(const int* __restrict__ ei,
                                               int* __restrict__ cpos,
                                               unsigned int* __restrict__ stage,
                                               int E, int NBUK) {
    __shared__ int h[512];
    __shared__ int base[512];
    int t = threadIdx.x;
    for (int i = t; i < NBUK; i += 256) h[i] = 0;
    __syncthreads();
    int e0 = blockIdx.x * 8192;
    int e1 = min(e0 + 8192, E);
    for (int e = e0 + t; e < e1; e += 256) atomicAdd(&h[ei[E + e] >> 8], 1);
    __syncthreads();
    for (int b = t; b < NBUK; b += 256) {
        int c = h[b];
        base[b] = c ? atomicAdd(&cpos[b], c) : 0;
        h[b] = 0;
    }
    __syncthreads();
    for (int e = e0 + t; e < e1; e += 256) {
        unsigned int s = (unsigned int)ei[e];
        int d = ei[E + e];
        int b = d >> 8;
        int off = base[b] + atomicAdd(&h[b], 1);
        stage[off] = ((unsigned int)(d & 255) << 24) | s;
    }
}

// ---------------- B1: per-bucket node counts (LDS atomics) -> row_start, dinv

__global__ __launch_bounds__(256) void k_B1(const unsigned int* __restrict__ stage,
                                            const int* __restrict__ cbase,
                                            int* __restrict__ row_start,
                                            float* __restrict__ dinv, int N) {
    __shared__ int cnt[256];
    __shared__ int sd[256];
    int b = blockIdx.x;
    int n0 = b << 8;
    int t = threadIdx.x;
    cnt[t] = 0;
    __syncthreads();
    int s0 = cbase[b], s1 = cbase[b + 1];
    for (int j = s0 + t; j < s1; j += 256) atomicAdd(&cnt[stage[j] >> 24], 1);
    __syncthreads();
    int c = cnt[t];
    sd[t] = c;
    __syncthreads();
    for (int off = 1; off < 256; off <<= 1) {
        int u = (t >= off) ? sd[t - off] : 0;
        __syncthreads();
        sd[t] += u;
        __syncthreads();
    }
    int excl = sd[t] - c;
    int node = n0 + t;
    if (node < N) {
        row_start[node] = s0 + excl;
        dinv[node] = 1.0f / sqrtf((float)(c + 1));   // +1 self-loop
    }
}

// ---------------- B2: fine scatter within bucket -> ep = (src, norm) --------

__global__ __launch_bounds__(256) void k_B2(const unsigned int* __restrict__ stage,
                                            const int* __restrict__ cbase,
                                            const int* __restrict__ row_start,
                                            const float* __restrict__ dinv,
                                            int2* __restrict__ ep, int N) {
    __shared__ int lpos[256];
    __shared__ float ld[256];
    int b = blockIdx.x;
    int n0 = b << 8;
    int t = threadIdx.x;
    int node = n0 + t;
    if (node < N) {
        lpos[t] = row_start[node];
        ld[t] = dinv[node];
    }
    __syncthreads();
    int s0 = cbase[b], s1 = cbase[b + 1];
    for (int j = s0 + t; j < s1; j += 256) {
        unsigned int v = stage[j];
        int li = v >> 24;
        int src = v & 0xFFFFFF;
        int slot = atomicAdd(&lpos[li], 1);
        ep[slot] = make_int2(src, __float_as_int(dinv[src] * ld[li]));
    }
}

// ---------------- GEMM (fp32 input): Y[N,OUT](fp16) = X[N,K] @ W[K,OUT] -----
// 64x64 tile per 256-thread block, 4x4 register tile, K tiled by 32.
// Thread rows {ty,ty+16,ty+32,ty+48}: A-tile LDS reads spread all 32 banks.

template <int K, int OUT>
__global__ __launch_bounds__(256) void k_gemm32(const float* __restrict__ X,
                                                const float* __restrict__ W,
                                                __half* __restrict__ Y, int N) {
    __shared__ float Wl[32 * 64];    // 8 KB slab, zero-padded cols
    __shared__ float Al[64 * 36];    // 9 KB, padded stride 36
    int tid = threadIdx.x;
    int tx = tid & 15;
    int ty = tid >> 4;
    int row0 = blockIdx.x * 64;

    float acc[4][4];
#pragma unroll
    for (int i = 0; i < 4; i++)
#pragma unroll
        for (int j = 0; j < 4; j++) acc[i][j] = 0.0f;

    for (int kt = 0; kt < K; kt += 32) {
        __syncthreads();
#pragma unroll
        for (int it = 0; it < 2; it++) {
            int idx = tid + it * 256;
            int k = idx >> 4;
            int c4 = (idx & 15) << 2;
            float4 v = make_float4(0.f, 0.f, 0.f, 0.f);
            if (c4 < OUT) v = *(const float4*)&W[(size_t)(kt + k) * OUT + c4];
            *(float4*)&Wl[k * 64 + c4] = v;
        }
#pragma unroll
        for (int it = 0; it < 2; it++) {
            int vid = tid + it * 256;
            int r = vid >> 3;
            int kk = (vid & 7) << 2;
            int row = row0 + r;
            float4 v = make_float4(0.f, 0.f, 0.f, 0.f);
            if (row < N) v = *(const float4*)&X[(size_t)row * K + kt + kk];
            *(float4*)&Al[r * 36 + kk] = v;
        }
        __syncthreads();
#pragma unroll
        for (int k = 0; k < 32; k += 4) {
            float4 a[4], w[4];
#pragma unroll
            for (int i = 0; i < 4; i++) a[i] = *(const float4*)&Al[(ty + 16 * i) * 36 + k];
#pragma unroll
            for (int j = 0; j < 4; j++) w[j] = *(const float4*)&Wl[(k + j) * 64 + 4 * tx];
#pragma unroll
            for (int i = 0; i < 4; i++) {
                acc[i][0] += a[i].x * w[0].x; acc[i][1] += a[i].x * w[0].y;
                acc[i][2] += a[i].x * w[0].z; acc[i][3] += a[i].x * w[0].w;
                acc[i][0] += a[i].y * w[1].x; acc[i][1] += a[i].y * w[1].y;
                acc[i][2] += a[i].y * w[1].z; acc[i][3] += a[i].y * w[1].w;
                acc[i][0] += a[i].z * w[2].x; acc[i][1] += a[i].z * w[2].y;
                acc[i][2] += a[i].z * w[2].z; acc[i][3] += a[i].z * w[2].w;
                acc[i][0] += a[i].w * w[3].x; acc[i][1] += a[i].w * w[3].y;
                acc[i][2] += a[i].w * w[3].z; acc[i][3] += a[i].w * w[3].w;
            }
        }
    }

    int c0 = 4 * tx;
#pragma unroll
    for (int i = 0; i < 4; i++) {
        int row = row0 + ty + 16 * i;
        if (row < N && c0 + 4 <= OUT) {
            __half2 p0 = __floats2half2_rn(acc[i][0], acc[i][1]);
            __half2 p1 = __floats2half2_rn(acc[i][2], acc[i][3]);
            uint2 pk = make_uint2(*(unsigned int*)&p0, *(unsigned int*)&p1);
            *(uint2*)&Y[(size_t)row * OUT + c0] = pk;
        }
    }
}

// ---------------- GEMM (fp16 input, K=64): Y[N,OUT](fp16) = X @ W -----------
// Full 64-K staged once; A converted fp16->fp32 during staging so the FMA
// loop is identical. LDS: 16 KB W + 17 KB A.

template <int OUT>
__global__ __launch_bounds__(256) void k_gemm16(const __half* __restrict__ X,
                                                const float* __restrict__ W,
                                                __half* __restrict__ Y, int N) {
    __shared__ float Wl[64 * 64];    // 16 KB, zero-padded cols
    __shared__ float Al[64 * 68];    // 17 KB, padded stride 68 (68%32==4)
    int tid = threadIdx.x;
    int tx = tid & 15;
    int ty = tid >> 4;
    int row0 = blockIdx.x * 64;

#pragma unroll
    for (int it = 0; it < 4; it++) {
        int idx = tid + it * 256;
        int k = idx >> 4;
        int c4 = (idx & 15) << 2;
        float4 v = make_float4(0.f, 0.f, 0.f, 0.f);
        if (c4 < OUT) v = *(const float4*)&W[(size_t)k * OUT + c4];
        *(float4*)&Wl[k * 64 + c4] = v;
    }
#pragma unroll
    for (int it = 0; it < 2; it++) {
        int idx = tid + it * 256;
        int r = idx >> 3;
        int c8 = (idx & 7) << 3;
        int row = row0 + r;
        uint4 hv = make_uint4(0, 0, 0, 0);
        if (row < N) hv = *(const uint4*)&X[(size_t)row * 64 + c8];
        __half2* hp = (__half2*)&hv;
        float2 f0 = __half22float2(hp[0]);
        float2 f1 = __half22float2(hp[1]);
        float2 f2 = __half22float2(hp[2]);
        float2 f3 = __half22float2(hp[3]);
        *(float4*)&Al[r * 68 + c8]     = make_float4(f0.x, f0.y, f1.x, f1.y);
        *(float4*)&Al[r * 68 + c8 + 4] = make_float4(f2.x, f2.y, f3.x, f3.y);
    }
    __syncthreads();

    float acc[4][4];
#pragma unroll
    for (int i = 0; i < 4; i++)
#pragma unroll
        for (int j = 0; j < 4; j++) acc[i][j] = 0.0f;

#pragma unroll
    for (int k = 0; k < 64; k += 4) {
        float4 a[4], w[4];
#pragma unroll
        for (int i = 0; i < 4; i++) a[i] = *(const float4*)&Al[(ty + 16 * i) * 68 + k];
#pragma unroll
        for (int j = 0; j < 4; j++) w[j] = *(const float4*)&Wl[(k + j) * 64 + 4 * tx];
#pragma unroll
        for (int i = 0; i < 4; i++) {
            acc[i][0] += a[i].x * w[0].x; acc[i][1] += a[i].x * w[0].y;
            acc[i][2] += a[i].x * w[0].z; acc[i][3] += a[i].x * w[0].w;
            acc[i][0] += a[i].y * w[1].x; acc[i][1] += a[i].y * w[1].y;
            acc[i][2] += a[i].y * w[1].z; acc[i][3] += a[i].y * w[1].w;
            acc[i][0] += a[i].z * w[2].x; acc[i][1] += a[i].z * w[2].y;
            acc[i][2] += a[i].z * w[2].z; acc[i][3] += a[i].z * w[2].w;
            acc[i][0] += a[i].w * w[3].x; acc[i][1] += a[i].w * w[3].y;
            acc[i][2] += a[i].w * w[3].z; acc[i][3] += a[i].w * w[3].w;
        }
    }

    int c0 = 4 * tx;
#pragma unroll
    for (int i = 0; i < 4; i++) {
        int row = row0 + ty + 16 * i;
        if (row < N && c0 + 4 <= OUT) {
            __half2 p0 = __floats2half2_rn(acc[i][0], acc[i][1]);
            __half2 p1 = __floats2half2_rn(acc[i][2], acc[i][3]);
            uint2 pk = make_uint2(*(unsigned int*)&p0, *(unsigned int*)&p1);
            *(uint2*)&Y[(size_t)row * OUT + c0] = pk;
        }
    }
}

// ---------------- Aggregation (fp16 gather, fp32 accumulate) ----------------
// 8 lanes/node (lane = 8 fp16 feats = 16B), 8 nodes/wave, unroll x8:
// up to 64 independent 16B gathers in flight per wave. ep = (src,norm) int2,
// plain sequential loads (R6 showed NT hints + dinv gathers regress).

__device__ __forceinline__ void fma8(float4& a0, float4& a1, uint4 hv, float w) {
    __half2* hp = (__half2*)&hv;
    float2 f0 = __half22float2(hp[0]);
    float2 f1 = __half22float2(hp[1]);
    float2 f2 = __half22float2(hp[2]);
    float2 f3 = __half22float2(hp[3]);
    a0.x += f0.x * w; a0.y += f0.y * w; a0.z += f1.x * w; a0.w += f1.y * w;
    a1.x += f2.x * w; a1.y += f2.y * w; a1.z += f3.x * w; a1.w += f3.y * w;
}

template <int NV, int F, int RELU, typename OutT>
__global__ __launch_bounds__(256) void k_agg(const __half* __restrict__ H,
                                             const int* __restrict__ row_start,
                                             const int2* __restrict__ ep,
                                             const float* __restrict__ dinv,
                                             const float* __restrict__ bias,
                                             OutT* __restrict__ out, int N) {
    int tid = threadIdx.x;
    int lane = tid & 63;
    int sub = lane >> 3;        // node within wave (0..7)
    int lq = lane & 7;          // 8-feature chunk
    int node = blockIdx.x * 32 + (tid >> 6) * 8 + sub;
    if (node >= N) return;
    const bool act = (NV == 8) || (lq < NV);

    int jb = row_start[node];
    int je = row_start[node + 1];
    float dv = dinv[node];

    float4 a0 = make_float4(0.f, 0.f, 0.f, 0.f);
    float4 a1 = make_float4(0.f, 0.f, 0.f, 0.f);
    if (act) {
        uint4 hv = *(const uint4*)&H[(size_t)node * F + 8 * lq];
        fma8(a0, a1, hv, dv * dv);
    }

    int j = jb;
    for (; j + 8 <= je; j += 8) {
        int2 e0 = ep[j],     e1 = ep[j + 1], e2 = ep[j + 2], e3 = ep[j + 3];
        int2 e4 = ep[j + 4], e5 = ep[j + 5], e6 = ep[j + 6], e7 = ep[j + 7];
        if (act) {
            uint4 h0 = *(const uint4*)&H[(size_t)e0.x * F + 8 * lq];
            uint4 h1 = *(const uint4*)&H[(size_t)e1.x * F + 8 * lq];
            uint4 h2 = *(const uint4*)&H[(size_t)e2.x * F + 8 * lq];
            uint4 h3 = *(const uint4*)&H[(size_t)e3.x * F + 8 * lq];
            uint4 h4 = *(const uint4*)&H[(size_t)e4.x * F + 8 * lq];
            uint4 h5 = *(const uint4*)&H[(size_t)e5.x * F + 8 * lq];
            uint4 h6 = *(const uint4*)&H[(size_t)e6.x * F + 8 * lq];
            uint4 h7 = *(const uint4*)&H[(size_t)e7.x * F + 8 * lq];
            fma8(a0, a1, h0, __int_as_float(e0.y));
            fma8(a0, a1, h1, __int_as_float(e1.y));
            fma8(a0, a1, h2, __int_as_float(e2.y));
            fma8(a0, a1, h3, __int_as_float(e3.y));
            fma8(a0, a1, h4, __int_as_float(e4.y));
            fma8(a0, a1, h5, __int_as_float(e5.y));
            fma8(a0, a1, h6, __int_as_float(e6.y));
            fma8(a0, a1, h7, __int_as_float(e7.y));
        }
    }
    for (; j + 2 <= je; j += 2) {
        int2 e0 = ep[j], e1 = ep[j + 1];
        if (act) {
            uint4 h0 = *(const uint4*)&H[(size_t)e0.x * F + 8 * lq];
            uint4 h1 = *(const uint4*)&H[(size_t)e1.x * F + 8 * lq];
            fma8(a0, a1, h0, __int_as_float(e0.y));
            fma8(a0, a1, h1, __int_as_float(e1.y));
        }
    }
    if (j < je) {
        int2 e = ep[j];
        if (act) {
            uint4 h = *(const uint4*)&H[(size_t)e.x * F + 8 * lq];
            fma8(a0, a1, h, __int_as_float(e.y));
        }
    }

    if (act) {
        float4 b0 = *(const float4*)&bias[8 * lq];
        float4 b1 = *(const float4*)&bias[8 * lq + 4];
        a0.x += b0.x; a0.y += b0.y; a0.z += b0.z; a0.w += b0.w;
        a1.x += b1.x; a1.y += b1.y; a1.z += b1.z; a1.w += b1.w;
        if (RELU) {
            a0.x = fmaxf(a0.x, 0.f); a0.y = fmaxf(a0.y, 0.f);
            a0.z = fmaxf(a0.z, 0.f); a0.w = fmaxf(a0.w, 0.f);
            a1.x = fmaxf(a1.x, 0.f); a1.y = fmaxf(a1.y, 0.f);
            a1.z = fmaxf(a1.z, 0.f); a1.w = fmaxf(a1.w, 0.f);
        }
        if constexpr (sizeof(OutT) == 2) {
            __half2 p0 = __floats2half2_rn(a0.x, a0.y);
            __half2 p1 = __floats2half2_rn(a0.z, a0.w);
            __half2 p2 = __floats2half2_rn(a1.x, a1.y);
            __half2 p3 = __floats2half2_rn(a1.z, a1.w);
            uint4 pk = make_uint4(*(unsigned int*)&p0, *(unsigned int*)&p1,
                                  *(unsigned int*)&p2, *(unsigned int*)&p3);
            *(uint4*)&out[(size_t)node * F + 8 * lq] = pk;
        } else {
            *(float4*)&out[(size_t)node * F + 8 * lq] = a0;
            *(float4*)&out[(size_t)node * F + 8 * lq + 4] = a1;
        }
    }
}

// ---------------- launch ----------------

extern "C" void kernel_launch(void* const* d_in, const int* in_sizes, int n_in,
                              void* d_out, int out_size, void* d_ws, size_t ws_size,
                              hipStream_t stream) {
    const float* x  = (const float*)d_in[0];
    const int*   ei = (const int*)d_in[1];
    const float* W0 = (const float*)d_in[2];
    const float* b0 = (const float*)d_in[3];
    const float* W1 = (const float*)d_in[4];
    const float* b1 = (const float*)d_in[5];
    const float* W2 = (const float*)d_in[6];
    const float* b2 = (const float*)d_in[7];
    float* out = (float*)d_out;

    const int N = in_sizes[0] / 128;
    const int E = in_sizes[1] / 2;
    const int NBUK = (N + 255) >> 8;   // coarse buckets of 256 nodes (<=512)

    char* w = (char*)d_ws;
    size_t off = 0;
    int*    ccnt      = (int*)(w + off);    off = ALIGN256(off + (size_t)NBUK * 4);
    int*    cbase     = (int*)(w + off);    off = ALIGN256(off + (size_t)(NBUK + 1) * 4);
    int*    cpos      = (int*)(w + off);    off = ALIGN256(off + (size_t)NBUK * 4);
    int*    row_start = (int*)(w + off);    off = ALIGN256(off + (size_t)(N + 1) * 4);
    float*  dinv      = (float*)(w + off);  off = ALIGN256(off + (size_t)N * 4);
    int2*   ep        = (int2*)(w + off);   off = ALIGN256(off + (size_t)E * 8);
    __half* bufH      = (__half*)(w + off); off = ALIGN256(off + (size_t)N * 64 * 2);
    __half* bufG      = (__half*)(w + off); off = ALIGN256(off + (size_t)N * 64 * 2);
    unsigned int* stage = (unsigned int*)bufG;   // dead before agg1 writes bufG

    const int gGemm = (N + 63) / 64;
    const int gAgg  = (N + 31) / 32;
    const int gPA   = (E + 8191) / 8192;

    hipMemsetAsync(ccnt, 0, (size_t)NBUK * 4, stream);
    k_gemm32<128, 64><<<gGemm, 256, 0, stream>>>(x, W0, bufH, N);
    k_coarse<<<gPA, 256, 0, stream>>>(ei, ccnt, E, NBUK);
    k_cscan<<<1, 256, 0, stream>>>(ccnt, cbase, cpos, row_start, NBUK, E, N);
    k_passA<<<gPA, 256, 0, stream>>>(ei, cpos, stage, E, NBUK);
    k_B1<<<NBUK, 256, 0, stream>>>(stage, cbase, row_start, dinv, N);
    k_B2<<<NBUK, 256, 0, stream>>>(stage, cbase, row_start, dinv, ep, N);

    k_agg<8, 64, 1, __half><<<gAgg, 256, 0, stream>>>(bufH, row_start, ep, dinv, b0, bufG, N);
    k_gemm16<64><<<gGemm, 256, 0, stream>>>(bufG, W1, bufH, N);
    k_agg<8, 64, 1, __half><<<gAgg, 256, 0, stream>>>(bufH, row_start, ep, dinv, b1, bufG, N);
    k_gemm16<40><<<gGemm, 256, 0, stream>>>(bufG, W2, bufH, N);
    k_agg<5, 40, 0, float><<<gAgg, 256, 0, stream>>>(bufH, row_start, ep, dinv, b2, out, N);
}

// Round 8
// 321.872 us; speedup vs baseline: 1.1975x; 1.1589x over previous
//
#include <hip/hip_runtime.h>
#include <hip/hip_fp16.h>

// GCN forward: 3x (GEMM -> normalized scatter-sum -> bias -> relu[except last])
// Gather table and agg<->gemm interfaces are fp16. ep = (src, norm) int2 —
// precomputed norm (R6: per-edge dinv gathers regress). k_gemm16 is K-tiled
// by 32 exactly like k_gemm32 (R7: one-shot K=64 staging -> 244 VGPR, 8%
// occupancy, 200K LDS conflicts). CSR built with zero global atomics.

#define ALIGN256(x) (((size_t)(x) + 255) & ~(size_t)255)

// ---------------- coarse histogram ----------------

__global__ __launch_bounds__(256) void k_coarse(const int* __restrict__ ei,
                                                int* __restrict__ ccnt,
                                                int E, int NBUK) {
    __shared__ int h[512];
    int t = threadIdx.x;
    for (int i = t; i < NBUK; i += 256) h[i] = 0;
    __syncthreads();
    int e0 = blockIdx.x * 8192;
    int e1 = min(e0 + 8192, E);
    for (int e = e0 + t; e < e1; e += 256) atomicAdd(&h[ei[E + e] >> 8], 1);
    __syncthreads();
    for (int i = t; i < NBUK; i += 256) {
        int c = h[i];
        if (c) atomicAdd(&ccnt[i], c);
    }
}

// ---------------- scan of coarse counts (single block, <=512 buckets) -------

__global__ __launch_bounds__(256) void k_cscan(const int* __restrict__ ccnt,
                                               int* __restrict__ cbase,
                                               int* __restrict__ cpos,
                                               int* __restrict__ row_start,
                                               int NBUK, int E, int N) {
    __shared__ int sd[256];
    int t = threadIdx.x;
    int i0 = 2 * t, i1 = 2 * t + 1;
    int v0 = (i0 < NBUK) ? ccnt[i0] : 0;
    int v1 = (i1 < NBUK) ? ccnt[i1] : 0;
    int s = v0 + v1;
    sd[t] = s;
    __syncthreads();
    for (int off = 1; off < 256; off <<= 1) {
        int u = (t >= off) ? sd[t - off] : 0;
        __syncthreads();
        sd[t] += u;
        __syncthreads();
    }
    int base = sd[t] - s;
    if (i0 < NBUK) { cbase[i0] = base;      cpos[i0] = base; }
    if (i1 < NBUK) { cbase[i1] = base + v0; cpos[i1] = base + v0; }
    if (t == 0) { cbase[NBUK] = E; row_start[N] = E; }
}

// ---------------- pass A: coarse scatter; stage entry = (dst&255)<<24 | src -

__global__ __launch_bounds__(256) void k_passA(const int* __restrict__ ei,
                                               int* __restrict__ cpos,
                                               unsigned int* __restrict__ stage,
                                               int E, int NBUK) {
    __shared__ int h[512];
    __shared__ int base[512];
    int t = threadIdx.x;
    for (int i = t; i < NBUK; i += 256) h[i] = 0;
    __syncthreads();
    int e0 = blockIdx.x * 8192;
    int e1 = min(e0 + 8192, E);
    for (int e = e0 + t; e < e1; e += 256) atomicAdd(&h[ei[E + e] >> 8], 1);
    __syncthreads();
    for (int b = t; b < NBUK; b += 256) {
        int c = h[b];
        base[b] = c ? atomicAdd(&cpos[b], c) : 0;
        h[b] = 0;
    }
    __syncthreads();
    for (int e = e0 + t; e < e1; e += 256) {
        unsigned int s = (unsigned int)ei[e];
        int d = ei[E + e];
        int b = d >> 8;
        int off = base[b] + atomicAdd(&h[b], 1);
        stage[off] = ((unsigned int)(d & 255) << 24) | s;
    }
}

// ---------------- B1: per-bucket node counts (LDS atomics) -> row_start, dinv

__global__ __launch_bounds__(256) void k_B1(const unsigned int* __restrict__ stage,
                                            const int* __restrict__ cbase,
                                            int* __restrict__ row_start,
                                            float* __restrict__ dinv, int N) {
    __shared__ int cnt[256];
    __shared__ int sd[256];
    int b = blockIdx.x;
    int n0 = b << 8;
    int t = threadIdx.x;
    cnt[t] = 0;
    __syncthreads();
    int s0 = cbase[b], s1 = cbase[b + 1];
    for (int j = s0 + t; j < s1; j += 256) atomicAdd(&cnt[stage[j] >> 24], 1);
    __syncthreads();
    int c = cnt[t];
    sd[t] = c;
    __syncthreads();
    for (int off = 1; off < 256; off <<= 1) {
        int u = (t >= off) ? sd[t - off] : 0;
        __syncthreads();
        sd[t] += u;
        __syncthreads();
    }
    int excl = sd[t] - c;
    int node = n0 + t;
    if (node < N) {
        row_start[node] = s0 + excl;
        dinv[node] = 1.0f / sqrtf((float)(c + 1));   // +1 self-loop
    }
}

// ---------------- B2: fine scatter within bucket -> ep = (src, norm) --------

__global__ __launch_bounds__(256) void k_B2(const unsigned int* __restrict__ stage,
                                            const int* __restrict__ cbase,
                                            const int* __restrict__ row_start,
                                            const float* __restrict__ dinv,
                                            int2* __restrict__ ep, int N) {
    __shared__ int lpos[256];
    __shared__ float ld[256];
    int b = blockIdx.x;
    int n0 = b << 8;
    int t = threadIdx.x;
    int node = n0 + t;
    if (node < N) {
        lpos[t] = row_start[node];
        ld[t] = dinv[node];
    }
    __syncthreads();
    int s0 = cbase[b], s1 = cbase[b + 1];
    for (int j = s0 + t; j < s1; j += 256) {
        unsigned int v = stage[j];
        int li = v >> 24;
        int src = v & 0xFFFFFF;
        int slot = atomicAdd(&lpos[li], 1);
        ep[slot] = make_int2(src, __float_as_int(dinv[src] * ld[li]));
    }
}

// ---------------- GEMM (fp32 input): Y[N,OUT](fp16) = X[N,K] @ W[K,OUT] -----
// 64x64 tile per 256-thread block, 4x4 register tile, K tiled by 32.
// Thread rows {ty,ty+16,ty+32,ty+48}: A-tile LDS reads spread all 32 banks.

template <int K, int OUT>
__global__ __launch_bounds__(256) void k_gemm32(const float* __restrict__ X,
                                                const float* __restrict__ W,
                                                __half* __restrict__ Y, int N) {
    __shared__ float Wl[32 * 64];    // 8 KB slab, zero-padded cols
    __shared__ float Al[64 * 36];    // 9 KB, padded stride 36
    int tid = threadIdx.x;
    int tx = tid & 15;
    int ty = tid >> 4;
    int row0 = blockIdx.x * 64;

    float acc[4][4];
#pragma unroll
    for (int i = 0; i < 4; i++)
#pragma unroll
        for (int j = 0; j < 4; j++) acc[i][j] = 0.0f;

    for (int kt = 0; kt < K; kt += 32) {
        __syncthreads();
#pragma unroll
        for (int it = 0; it < 2; it++) {
            int idx = tid + it * 256;
            int k = idx >> 4;
            int c4 = (idx & 15) << 2;
            float4 v = make_float4(0.f, 0.f, 0.f, 0.f);
            if (c4 < OUT) v = *(const float4*)&W[(size_t)(kt + k) * OUT + c4];
            *(float4*)&Wl[k * 64 + c4] = v;
        }
#pragma unroll
        for (int it = 0; it < 2; it++) {
            int vid = tid + it * 256;
            int r = vid >> 3;
            int kk = (vid & 7) << 2;
            int row = row0 + r;
            float4 v = make_float4(0.f, 0.f, 0.f, 0.f);
            if (row < N) v = *(const float4*)&X[(size_t)row * K + kt + kk];
            *(float4*)&Al[r * 36 + kk] = v;
        }
        __syncthreads();
#pragma unroll
        for (int k = 0; k < 32; k += 4) {
            float4 a[4], w[4];
#pragma unroll
            for (int i = 0; i < 4; i++) a[i] = *(const float4*)&Al[(ty + 16 * i) * 36 + k];
#pragma unroll
            for (int j = 0; j < 4; j++) w[j] = *(const float4*)&Wl[(k + j) * 64 + 4 * tx];
#pragma unroll
            for (int i = 0; i < 4; i++) {
                acc[i][0] += a[i].x * w[0].x; acc[i][1] += a[i].x * w[0].y;
                acc[i][2] += a[i].x * w[0].z; acc[i][3] += a[i].x * w[0].w;
                acc[i][0] += a[i].y * w[1].x; acc[i][1] += a[i].y * w[1].y;
                acc[i][2] += a[i].y * w[1].z; acc[i][3] += a[i].y * w[1].w;
                acc[i][0] += a[i].z * w[2].x; acc[i][1] += a[i].z * w[2].y;
                acc[i][2] += a[i].z * w[2].z; acc[i][3] += a[i].z * w[2].w;
                acc[i][0] += a[i].w * w[3].x; acc[i][1] += a[i].w * w[3].y;
                acc[i][2] += a[i].w * w[3].z; acc[i][3] += a[i].w * w[3].w;
            }
        }
    }

    int c0 = 4 * tx;
#pragma unroll
    for (int i = 0; i < 4; i++) {
        int row = row0 + ty + 16 * i;
        if (row < N && c0 + 4 <= OUT) {
            __half2 p0 = __floats2half2_rn(acc[i][0], acc[i][1]);
            __half2 p1 = __floats2half2_rn(acc[i][2], acc[i][3]);
            uint2 pk = make_uint2(*(unsigned int*)&p0, *(unsigned int*)&p1);
            *(uint2*)&Y[(size_t)row * OUT + c0] = pk;
        }
    }
}

// ---------------- GEMM (fp16 input, K=64): same structure as k_gemm32 -------
// Only difference: A-staging loads uint2 (4 fp16) and converts to float4.

template <int OUT>
__global__ __launch_bounds__(256) void k_gemm16(const __half* __restrict__ X,
                                                const float* __restrict__ W,
                                                __half* __restrict__ Y, int N) {
    __shared__ float Wl[32 * 64];    // 8 KB slab, zero-padded cols
    __shared__ float Al[64 * 36];    // 9 KB, padded stride 36
    int tid = threadIdx.x;
    int tx = tid & 15;
    int ty = tid >> 4;
    int row0 = blockIdx.x * 64;

    float acc[4][4];
#pragma unroll
    for (int i = 0; i < 4; i++)
#pragma unroll
        for (int j = 0; j < 4; j++) acc[i][j] = 0.0f;

    for (int kt = 0; kt < 64; kt += 32) {
        __syncthreads();
#pragma unroll
        for (int it = 0; it < 2; it++) {
            int idx = tid + it * 256;
            int k = idx >> 4;
            int c4 = (idx & 15) << 2;
            float4 v = make_float4(0.f, 0.f, 0.f, 0.f);
            if (c4 < OUT) v = *(const float4*)&W[(size_t)(kt + k) * OUT + c4];
            *(float4*)&Wl[k * 64 + c4] = v;
        }
#pragma unroll
        for (int it = 0; it < 2; it++) {
            int vid = tid + it * 256;
            int r = vid >> 3;
            int kk = (vid & 7) << 2;
            int row = row0 + r;
            uint2 hv = make_uint2(0, 0);
            if (row < N) hv = *(const uint2*)&X[(size_t)row * 64 + kt + kk];
            __half2* hp = (__half2*)&hv;
            float2 f0 = __half22float2(hp[0]);
            float2 f1 = __half22float2(hp[1]);
            *(float4*)&Al[r * 36 + kk] = make_float4(f0.x, f0.y, f1.x, f1.y);
        }
        __syncthreads();
#pragma unroll
        for (int k = 0; k < 32; k += 4) {
            float4 a[4], w[4];
#pragma unroll
            for (int i = 0; i < 4; i++) a[i] = *(const float4*)&Al[(ty + 16 * i) * 36 + k];
#pragma unroll
            for (int j = 0; j < 4; j++) w[j] = *(const float4*)&Wl[(k + j) * 64 + 4 * tx];
#pragma unroll
            for (int i = 0; i < 4; i++) {
                acc[i][0] += a[i].x * w[0].x; acc[i][1] += a[i].x * w[0].y;
                acc[i][2] += a[i].x * w[0].z; acc[i][3] += a[i].x * w[0].w;
                acc[i][0] += a[i].y * w[1].x; acc[i][1] += a[i].y * w[1].y;
                acc[i][2] += a[i].y * w[1].z; acc[i][3] += a[i].y * w[1].w;
                acc[i][0] += a[i].z * w[2].x; acc[i][1] += a[i].z * w[2].y;
                acc[i][2] += a[i].z * w[2].z; acc[i][3] += a[i].z * w[2].w;
                acc[i][0] += a[i].w * w[3].x; acc[i][1] += a[i].w * w[3].y;
                acc[i][2] += a[i].w * w[3].z; acc[i][3] += a[i].w * w[3].w;
            }
        }
    }

    int c0 = 4 * tx;
#pragma unroll
    for (int i = 0; i < 4; i++) {
        int row = row0 + ty + 16 * i;
        if (row < N && c0 + 4 <= OUT) {
            __half2 p0 = __floats2half2_rn(acc[i][0], acc[i][1]);
            __half2 p1 = __floats2half2_rn(acc[i][2], acc[i][3]);
            uint2 pk = make_uint2(*(unsigned int*)&p0, *(unsigned int*)&p1);
            *(uint2*)&Y[(size_t)row * OUT + c0] = pk;
        }
    }
}

// ---------------- Aggregation (fp16 gather, fp32 accumulate) ----------------
// 8 lanes/node (lane = 8 fp16 feats = 16B), 8 nodes/wave, unroll x8:
// up to 64 independent 16B gathers in flight per wave. ep = (src,norm) int2.

__device__ __forceinline__ void fma8(float4& a0, float4& a1, uint4 hv, float w) {
    __half2* hp = (__half2*)&hv;
    float2 f0 = __half22float2(hp[0]);
    float2 f1 = __half22float2(hp[1]);
    float2 f2 = __half22float2(hp[2]);
    float2 f3 = __half22float2(hp[3]);
    a0.x += f0.x * w; a0.y += f0.y * w; a0.z += f1.x * w; a0.w += f1.y * w;
    a1.x += f2.x * w; a1.y += f2.y * w; a1.z += f3.x * w; a1.w += f3.y * w;
}

template <int NV, int F, int RELU, typename OutT>
__global__ __launch_bounds__(256) void k_agg(const __half* __restrict__ H,
                                             const int* __restrict__ row_start,
                                             const int2* __restrict__ ep,
                                             const float* __restrict__ dinv,
                                             const float* __restrict__ bias,
                                             OutT* __restrict__ out, int N) {
    int tid = threadIdx.x;
    int lane = tid & 63;
    int sub = lane >> 3;        // node within wave (0..7)
    int lq = lane & 7;          // 8-feature chunk
    int node = blockIdx.x * 32 + (tid >> 6) * 8 + sub;
    if (node >= N) return;
    const bool act = (NV == 8) || (lq < NV);

    int jb = row_start[node];
    int je = row_start[node + 1];
    float dv = dinv[node];

    float4 a0 = make_float4(0.f, 0.f, 0.f, 0.f);
    float4 a1 = make_float4(0.f, 0.f, 0.f, 0.f);
    if (act) {
        uint4 hv = *(const uint4*)&H[(size_t)node * F + 8 * lq];
        fma8(a0, a1, hv, dv * dv);
    }

    int j = jb;
    for (; j + 8 <= je; j += 8) {
        int2 e0 = ep[j],     e1 = ep[j + 1], e2 = ep[j + 2], e3 = ep[j + 3];
        int2 e4 = ep[j + 4], e5 = ep[j + 5], e6 = ep[j + 6], e7 = ep[j + 7];
        if (act) {
            uint4 h0 = *(const uint4*)&H[(size_t)e0.x * F + 8 * lq];
            uint4 h1 = *(const uint4*)&H[(size_t)e1.x * F + 8 * lq];
            uint4 h2 = *(const uint4*)&H[(size_t)e2.x * F + 8 * lq];
            uint4 h3 = *(const uint4*)&H[(size_t)e3.x * F + 8 * lq];
            uint4 h4 = *(const uint4*)&H[(size_t)e4.x * F + 8 * lq];
            uint4 h5 = *(const uint4*)&H[(size_t)e5.x * F + 8 * lq];
            uint4 h6 = *(const uint4*)&H[(size_t)e6.x * F + 8 * lq];
            uint4 h7 = *(const uint4*)&H[(size_t)e7.x * F + 8 * lq];
            fma8(a0, a1, h0, __int_as_float(e0.y));
            fma8(a0, a1, h1, __int_as_float(e1.y));
            fma8(a0, a1, h2, __int_as_float(e2.y));
            fma8(a0, a1, h3, __int_as_float(e3.y));
            fma8(a0, a1, h4, __int_as_float(e4.y));
            fma8(a0, a1, h5, __int_as_float(e5.y));
            fma8(a0, a1, h6, __int_as_float(e6.y));
            fma8(a0, a1, h7, __int_as_float(e7.y));
        }
    }
    for (; j + 2 <= je; j += 2) {
        int2 e0 = ep[j], e1 = ep[j + 1];
        if (act) {
            uint4 h0 = *(const uint4*)&H[(size_t)e0.x * F + 8 * lq];
            uint4 h1 = *(const uint4*)&H[(size_t)e1.x * F + 8 * lq];
            fma8(a0, a1, h0, __int_as_float(e0.y));
            fma8(a0, a1, h1, __int_as_float(e1.y));
        }
    }
    if (j < je) {
        int2 e = ep[j];
        if (act) {
            uint4 h = *(const uint4*)&H[(size_t)e.x * F + 8 * lq];
            fma8(a0, a1, h, __int_as_float(e.y));
        }
    }

    if (act) {
        float4 b0 = *(const float4*)&bias[8 * lq];
        float4 b1 = *(const float4*)&bias[8 * lq + 4];
        a0.x += b0.x; a0.y += b0.y; a0.z += b0.z; a0.w += b0.w;
        a1.x += b1.x; a1.y += b1.y; a1.z += b1.z; a1.w += b1.w;
        if (RELU) {
            a0.x = fmaxf(a0.x, 0.f); a0.y = fmaxf(a0.y, 0.f);
            a0.z = fmaxf(a0.z, 0.f); a0.w = fmaxf(a0.w, 0.f);
            a1.x = fmaxf(a1.x, 0.f); a1.y = fmaxf(a1.y, 0.f);
            a1.z = fmaxf(a1.z, 0.f); a1.w = fmaxf(a1.w, 0.f);
        }
        if constexpr (sizeof(OutT) == 2) {
            __half2 p0 = __floats2half2_rn(a0.x, a0.y);
            __half2 p1 = __floats2half2_rn(a0.z, a0.w);
            __half2 p2 = __floats2half2_rn(a1.x, a1.y);
            __half2 p3 = __floats2half2_rn(a1.z, a1.w);
            uint4 pk = make_uint4(*(unsigned int*)&p0, *(unsigned int*)&p1,
                                  *(unsigned int*)&p2, *(unsigned int*)&p3);
            *(uint4*)&out[(size_t)node * F + 8 * lq] = pk;
        } else {
            *(float4*)&out[(size_t)node * F + 8 * lq] = a0;
            *(float4*)&out[(size_t)node * F + 8 * lq + 4] = a1;
        }
    }
}

// ---------------- launch ----------------

extern "C" void kernel_launch(void* const* d_in, const int* in_sizes, int n_in,
                              void* d_out, int out_size, void* d_ws, size_t ws_size,
                              hipStream_t stream) {
    const float* x  = (const float*)d_in[0];
    const int*   ei = (const int*)d_in[1];
    const float* W0 = (const float*)d_in[2];
    const float* b0 = (const float*)d_in[3];
    const float* W1 = (const float*)d_in[4];
    const float* b1 = (const float*)d_in[5];
    const float* W2 = (const float*)d_in[6];
    const float* b2 = (const float*)d_in[7];
    float* out = (float*)d_out;

    const int N = in_sizes[0] / 128;
    const int E = in_sizes[1] / 2;
    const int NBUK = (N + 255) >> 8;   // coarse buckets of 256 nodes (<=512)

    char* w = (char*)d_ws;
    size_t off = 0;
    int*    ccnt      = (int*)(w + off);    off = ALIGN256(off + (size_t)NBUK * 4);
    int*    cbase     = (int*)(w + off);    off = ALIGN256(off + (size_t)(NBUK + 1) * 4);
    int*    cpos      = (int*)(w + off);    off = ALIGN256(off + (size_t)NBUK * 4);
    int*    row_start = (int*)(w + off);    off = ALIGN256(off + (size_t)(N + 1) * 4);
    float*  dinv      = (float*)(w + off);  off = ALIGN256(off + (size_t)N * 4);
    int2*   ep        = (int2*)(w + off);   off = ALIGN256(off + (size_t)E * 8);
    __half* bufH      = (__half*)(w + off); off = ALIGN256(off + (size_t)N * 64 * 2);
    __half* bufG      = (__half*)(w + off); off = ALIGN256(off + (size_t)N * 64 * 2);
    unsigned int* stage = (unsigned int*)bufG;   // dead before agg1 writes bufG

    const int gGemm = (N + 63) / 64;
    const int gAgg  = (N + 31) / 32;
    const int gPA   = (E + 8191) / 8192;

    hipMemsetAsync(ccnt, 0, (size_t)NBUK * 4, stream);
    k_gemm32<128, 64><<<gGemm, 256, 0, stream>>>(x, W0, bufH, N);
    k_coarse<<<gPA, 256, 0, stream>>>(ei, ccnt, E, NBUK);
    k_cscan<<<1, 256, 0, stream>>>(ccnt, cbase, cpos, row_start, NBUK, E, N);
    k_passA<<<gPA, 256, 0, stream>>>(ei, cpos, stage, E, NBUK);
    k_B1<<<NBUK, 256, 0, stream>>>(stage, cbase, row_start, dinv, N);
    k_B2<<<NBUK, 256, 0, stream>>>(stage, cbase, row_start, dinv, ep, N);

    k_agg<8, 64, 1, __half><<<gAgg, 256, 0, stream>>>(bufH, row_start, ep, dinv, b0, bufG, N);
    k_gemm16<64><<<gGemm, 256, 0, stream>>>(bufG, W1, bufH, N);
    k_agg<8, 64, 1, __half><<<gAgg, 256, 0, stream>>>(bufH, row_start, ep, dinv, b1, bufG, N);
    k_gemm16<40><<<gGemm, 256, 0, stream>>>(bufG, W2, bufH, N);
    k_agg<5, 40, 0, float><<<gAgg, 256, 0, stream>>>(bufH, row_start, ep, dinv, b2, out, N);
}